// Round 9
// baseline (56.999 us; speedup 1.0000x reference)
//
#include <hip/hip_runtime.h>

// ForegroundConsistencyLoss — N=8192, C=20.
// loss = mean over pairs {both fg, d2>4} of relu(cos_sim(logits_i, logits_j)).
//
// v3: upper-triangle tiles only (x2 weight off-diagonal; diagonal once —
// self-pairs auto-excluded since d2_ii=0<4), single fused reduction via
// fixed-point u64 atomics + ticket (bit-deterministic), 2 kernels total.
//
// MFMA: sim = LN·LN^T (K=20 pad 32, bf16); d2 via augmented operands
// A'=[-2x,-2y,-2z,sq',1], B'=[x,y,z,1,sq'], sq' = fg ? |p|^2 : -1e30
// (sentinel folds the fg mask into the d2>4 test). Verified round 8:
// absmax 0.0 with this exact fragment convention.

#define C_CLS 20

typedef __attribute__((ext_vector_type(8)))  short bh8;    // 8 bf16 (4 VGPRs)
typedef __attribute__((ext_vector_type(16))) float fx16;   // 16 f32 acc

static __device__ __forceinline__ short f2bf(float x) {
    unsigned u = __float_as_uint(x);
    unsigned r = (u + 0x7fffu + ((u >> 16) & 1u)) >> 16;
    return (short)r;
}

struct FclAcc {
    unsigned long long sum_fix;   // sum * 2^20, fixed-point
    unsigned int cnt;
    unsigned int ticket;
};

__global__ void __launch_bounds__(256) fcl_prep(const float* __restrict__ pc,
                                                const float* __restrict__ logits,
                                                short* __restrict__ fragS,
                                                short* __restrict__ fragDA,
                                                short* __restrict__ fragDB,
                                                FclAcc* __restrict__ acc, int n) {
    int i = blockIdx.x * blockDim.x + threadIdx.x;
    if (i == 0) { acc->sum_fix = 0ull; acc->cnt = 0u; acc->ticket = 0u; }
    if (i >= n) return;
    const float* lg = logits + i * C_CLS;
    float l[C_CLS];
#pragma unroll
    for (int k = 0; k < C_CLS; ++k) l[k] = lg[k];
    float m = l[1];
#pragma unroll
    for (int k = 2; k < C_CLS; ++k) m = fmaxf(m, l[k]);
    bool fg = m > l[0];                 // argmax != 0 (ties -> index 0 -> bg)
    float ss = 0.f;
#pragma unroll
    for (int k = 0; k < C_CLS; ++k) ss = fmaf(l[k], l[k], ss);
    float inv = 1.0f / fmaxf(sqrtf(ss), 1e-8f);
    float px = pc[i * 3 + 0], py = pc[i * 3 + 1], pz = pc[i * 3 + 2];
    float sq = px * px + py * py + pz * pz;
    float sqp = fg ? sq : -1.0e30f;

    int g = i >> 5, r = i & 31;
    short* s0a = fragS + (((g * 2 + 0) * 64 + r) * 8);        // k 0..7
    short* s0b = fragS + (((g * 2 + 0) * 64 + r + 32) * 8);   // k 8..15
    short* s1a = fragS + (((g * 2 + 1) * 64 + r) * 8);        // k 16..23
    short* s1b = fragS + (((g * 2 + 1) * 64 + r + 32) * 8);   // k 24..31
#pragma unroll
    for (int e = 0; e < 8; ++e) {
        s0a[e] = f2bf(l[e] * inv);
        s0b[e] = f2bf(l[8 + e] * inv);
        s1a[e] = (e < 4) ? f2bf(l[16 + e] * inv) : (short)0;
        s1b[e] = (short)0;
    }
    short* daa = fragDA + ((g * 64 + r) * 8);
    short* dab = fragDA + ((g * 64 + r + 32) * 8);
    short* dba = fragDB + ((g * 64 + r) * 8);
    short* dbb = fragDB + ((g * 64 + r + 32) * 8);
    daa[0] = f2bf(-2.0f * px); daa[1] = f2bf(-2.0f * py); daa[2] = f2bf(-2.0f * pz);
    daa[3] = f2bf(sqp);        daa[4] = f2bf(1.0f);
    daa[5] = 0; daa[6] = 0; daa[7] = 0;
    dba[0] = f2bf(px); dba[1] = f2bf(py); dba[2] = f2bf(pz);
    dba[3] = f2bf(1.0f); dba[4] = f2bf(sqp);
    dba[5] = 0; dba[6] = 0; dba[7] = 0;
#pragma unroll
    for (int e = 0; e < 8; ++e) { dab[e] = 0; dbb[e] = 0; }
}

// tiles: (rg, cg) with cg >= rg, rg,cg in [0, NG).  T = NG*(NG+1)/2.
// linearized row-major: S(rg) = rg*NG - rg*(rg-1)/2 tiles precede row rg.
__global__ void __launch_bounds__(256) fcl_pairs(const short* __restrict__ fragS,
                                                 const short* __restrict__ fragDA,
                                                 const short* __restrict__ fragDB,
                                                 FclAcc* __restrict__ acc,
                                                 float* __restrict__ out,
                                                 int NG, int T, int nblocks) {
    const int tid = threadIdx.x;
    const int lane = tid & 63;
    const int w = blockIdx.x * 4 + (tid >> 6);

    const bh8* fS  = (const bh8*)fragS;
    const bh8* fDA = (const bh8*)fragDA;
    const bh8* fDB = (const bh8*)fragDB;

    float psD = 0.f, psO = 0.f;     // diagonal-tile / off-diagonal-tile sums
    int   cnD = 0,   cnO = 0;

    const int t0 = w * 8;
    // seed rg from sqrt, then fix up (wave-uniform scalar math)
    double gn = (double)NG + 0.5;
    double disc = gn * gn - 2.0 * (double)t0;
    int rg = (disc > 0.0) ? (int)((double)NG + 0.5 - sqrt(disc)) : NG - 1;
    if (rg < 0) rg = 0;
    if (rg > NG - 1) rg = NG - 1;
    int S = rg * NG - (rg * (rg - 1)) / 2;
    while (S > t0) { --rg; S -= NG - rg; }
    while (rg < NG - 1 && S + (NG - rg) <= t0) { S += NG - rg; ++rg; }

    int rg_cur = -1;
    bh8 aS0, aS1, aD;

    for (int k = 0; k < 8; ++k) {
        int t = t0 + k;
        if (t >= T) break;
        while (S + (NG - rg) <= t) { S += NG - rg; ++rg; }   // advance row
        int cg = rg + (t - S);

        if (rg != rg_cur) {          // wave-uniform: reload A fragments
            aS0 = fS[(rg * 2 + 0) * 64 + lane];
            aS1 = fS[(rg * 2 + 1) * 64 + lane];
            aD  = fDA[rg * 64 + lane];
            rg_cur = rg;
        }
        bh8 bS0 = fS[(cg * 2 + 0) * 64 + lane];
        bh8 bS1 = fS[(cg * 2 + 1) * 64 + lane];
        bh8 bD  = fDB[cg * 64 + lane];

        fx16 accS = {0.f};
        accS = __builtin_amdgcn_mfma_f32_32x32x16_bf16(aS0, bS0, accS, 0, 0, 0);
        accS = __builtin_amdgcn_mfma_f32_32x32x16_bf16(aS1, bS1, accS, 0, 0, 0);
        fx16 accD = {0.f};
        accD = __builtin_amdgcn_mfma_f32_32x32x16_bf16(aD, bD, accD, 0, 0, 0);

        if (rg == cg) {
#pragma unroll
            for (int r2 = 0; r2 < 16; ++r2) {
                bool c = accD[r2] > 4.0f;
                psD += c ? fmaxf(accS[r2], 0.f) : 0.f;
                cnD += c ? 1 : 0;
            }
        } else {
#pragma unroll
            for (int r2 = 0; r2 < 16; ++r2) {
                bool c = accD[r2] > 4.0f;
                psO += c ? fmaxf(accS[r2], 0.f) : 0.f;
                cnO += c ? 1 : 0;
            }
        }
    }

    // wave reduce (64 lanes)
#pragma unroll
    for (int off = 32; off > 0; off >>= 1) {
        psD += __shfl_down(psD, off);
        psO += __shfl_down(psO, off);
        cnD += __shfl_down(cnD, off);
        cnO += __shfl_down(cnO, off);
    }
    __shared__ float spD[4], spO[4];
    __shared__ int   scD[4], scO[4];
    int wid = tid >> 6;
    if (lane == 0) { spD[wid] = psD; spO[wid] = psO; scD[wid] = cnD; scO[wid] = cnO; }
    __syncthreads();
    if (tid == 0) {
        double sD = (double)spD[0] + spD[1] + spD[2] + spD[3];
        double sO = (double)spO[0] + spO[1] + spO[2] + spO[3];
        int cD = scD[0] + scD[1] + scD[2] + scD[3];
        int cO = scO[0] + scO[1] + scO[2] + scO[3];
        double bs = sD + 2.0 * sO;                        // weight off-diag x2
        unsigned int bc = (unsigned int)(cD + 2 * cO);
        unsigned long long sfix = (unsigned long long)(bs * 1048576.0 + 0.5);
        atomicAdd(&acc->sum_fix, sfix);
        atomicAdd(&acc->cnt, bc);
        __threadfence();
        unsigned int old = atomicAdd(&acc->ticket, 1u);
        if (old == (unsigned int)(nblocks - 1)) {         // last block finalizes
            unsigned long long Sf = atomicAdd(&acc->sum_fix, 0ull);
            unsigned int Cf = atomicAdd(&acc->cnt, 0u);
            out[0] = (Cf > 0u) ? (float)((double)Sf / 1048576.0 / (double)Cf)
                               : 1.0f;
        }
    }
}

extern "C" void kernel_launch(void* const* d_in, const int* in_sizes, int n_in,
                              void* d_out, int out_size, void* d_ws, size_t ws_size,
                              hipStream_t stream) {
    const float* pc     = (const float*)d_in[0];  // [N,3]
    const float* logits = (const float*)d_in[1];  // [N,20]
    float* out = (float*)d_out;

    const int N = in_sizes[0] / 3;                // 8192
    const int NG = N / 32;                        // 256 row/col groups
    const int T = NG * (NG + 1) / 2;              // 32896 upper-tri tiles

    short* fragS  = (short*)d_ws;                 // 262144 shorts (512 KB)
    short* fragDA = fragS + 262144;               // 131072 shorts (256 KB)
    short* fragDB = fragDA + 131072;              // 131072 shorts (256 KB)
    FclAcc* acc   = (FclAcc*)(fragDB + 131072);   // 16 B, 8-aligned (1 MB offset)

    const int nwaves  = (T + 7) / 8;              // 4112
    const int nblocks = (nwaves + 3) / 4;         // 1028

    fcl_prep<<<(N + 255) / 256, 256, 0, stream>>>(pc, logits, fragS, fragDA, fragDB, acc, N);
    fcl_pairs<<<nblocks, 256, 0, stream>>>(fragS, fragDA, fragDB, acc, out, NG, T, nblocks);
}

// Round 11
// 25.803 us; speedup vs baseline: 2.2091x; 2.2091x over previous
//
#include <hip/hip_runtime.h>

// ForegroundConsistencyLoss — N=8192, C=20.
// loss = mean over pairs {both fg, d2>4} of relu(cos_sim(logits_i, logits_j)).
//
// v4: triangle tiles (verified exact in v3) + UNCONTENDED reduction
// (per-block partials + tiny final kernel, verified structure from v2).
// v3 post-mortem: 1028 blocks x 3 device-scope atomics to one cacheline
// serialized cross-XCD -> 48 us. Never again.
//
// MFMA: sim = LN·LN^T (K=20 pad 32, bf16); d2 via augmented operands
// A'=[-2x,-2y,-2z,sq',1], B'=[x,y,z,1,sq'], sq' = fg ? |p|^2 : -1e30.
// Fragment convention verified round 8 (absmax 0.0).

#define C_CLS 20

typedef __attribute__((ext_vector_type(8)))  short bh8;    // 8 bf16 (4 VGPRs)
typedef __attribute__((ext_vector_type(16))) float fx16;   // 16 f32 acc

static __device__ __forceinline__ short f2bf(float x) {
    unsigned u = __float_as_uint(x);
    unsigned r = (u + 0x7fffu + ((u >> 16) & 1u)) >> 16;
    return (short)r;
}

__global__ void __launch_bounds__(256) fcl_prep(const float* __restrict__ pc,
                                                const float* __restrict__ logits,
                                                short* __restrict__ fragS,
                                                short* __restrict__ fragDA,
                                                short* __restrict__ fragDB, int n) {
    int i = blockIdx.x * blockDim.x + threadIdx.x;
    if (i >= n) return;
    const float* lg = logits + i * C_CLS;
    float l[C_CLS];
#pragma unroll
    for (int k = 0; k < C_CLS; ++k) l[k] = lg[k];
    float m = l[1];
#pragma unroll
    for (int k = 2; k < C_CLS; ++k) m = fmaxf(m, l[k]);
    bool fg = m > l[0];                 // argmax != 0 (ties -> index 0 -> bg)
    float ss = 0.f;
#pragma unroll
    for (int k = 0; k < C_CLS; ++k) ss = fmaf(l[k], l[k], ss);
    float inv = 1.0f / fmaxf(sqrtf(ss), 1e-8f);
    float px = pc[i * 3 + 0], py = pc[i * 3 + 1], pz = pc[i * 3 + 2];
    float sq = px * px + py * py + pz * pz;
    float sqp = fg ? sq : -1.0e30f;

    int g = i >> 5, r = i & 31;
    short* s0a = fragS + (((g * 2 + 0) * 64 + r) * 8);        // k 0..7
    short* s0b = fragS + (((g * 2 + 0) * 64 + r + 32) * 8);   // k 8..15
    short* s1a = fragS + (((g * 2 + 1) * 64 + r) * 8);        // k 16..23
    short* s1b = fragS + (((g * 2 + 1) * 64 + r + 32) * 8);   // k 24..31
#pragma unroll
    for (int e = 0; e < 8; ++e) {
        s0a[e] = f2bf(l[e] * inv);
        s0b[e] = f2bf(l[8 + e] * inv);
        s1a[e] = (e < 4) ? f2bf(l[16 + e] * inv) : (short)0;
        s1b[e] = (short)0;
    }
    short* daa = fragDA + ((g * 64 + r) * 8);
    short* dab = fragDA + ((g * 64 + r + 32) * 8);
    short* dba = fragDB + ((g * 64 + r) * 8);
    short* dbb = fragDB + ((g * 64 + r + 32) * 8);
    daa[0] = f2bf(-2.0f * px); daa[1] = f2bf(-2.0f * py); daa[2] = f2bf(-2.0f * pz);
    daa[3] = f2bf(sqp);        daa[4] = f2bf(1.0f);
    daa[5] = 0; daa[6] = 0; daa[7] = 0;
    dba[0] = f2bf(px); dba[1] = f2bf(py); dba[2] = f2bf(pz);
    dba[3] = f2bf(1.0f); dba[4] = f2bf(sqp);
    dba[5] = 0; dba[6] = 0; dba[7] = 0;
#pragma unroll
    for (int e = 0; e < 8; ++e) { dab[e] = 0; dbb[e] = 0; }
}

// Upper-triangle tiles (rg<=cg), row-major linearization.
// S(rg) = rg*NG - rg*(rg-1)/2 tiles precede row rg.
__global__ void __launch_bounds__(256) fcl_pairs(const short* __restrict__ fragS,
                                                 const short* __restrict__ fragDA,
                                                 const short* __restrict__ fragDB,
                                                 float* __restrict__ psums,
                                                 int* __restrict__ pcnts,
                                                 int NG, int T) {
    const int tid = threadIdx.x;
    const int lane = tid & 63;
    const int w = blockIdx.x * 4 + (tid >> 6);

    const bh8* fS  = (const bh8*)fragS;
    const bh8* fDA = (const bh8*)fragDA;
    const bh8* fDB = (const bh8*)fragDB;

    float psD = 0.f, psO = 0.f;     // diagonal-tile / off-diagonal-tile sums
    int   cnD = 0,   cnO = 0;

    const int t0 = w * 8;
    // seed rg from sqrt, then exact fix-up (wave-uniform scalar math)
    double gn = (double)NG + 0.5;
    double disc = gn * gn - 2.0 * (double)t0;
    int rg = (disc > 0.0) ? (int)((double)NG + 0.5 - sqrt(disc)) : NG - 1;
    if (rg < 0) rg = 0;
    if (rg > NG - 1) rg = NG - 1;
    int S = rg * NG - (rg * (rg - 1)) / 2;
    while (S > t0) { --rg; S -= NG - rg; }
    while (rg < NG - 1 && S + (NG - rg) <= t0) { S += NG - rg; ++rg; }

    int rg_cur = -1;
    bh8 aS0, aS1, aD;

    for (int k = 0; k < 8; ++k) {
        int t = t0 + k;
        if (t >= T) break;
        while (S + (NG - rg) <= t) { S += NG - rg; ++rg; }   // advance row
        int cg = rg + (t - S);

        if (rg != rg_cur) {          // wave-uniform A reload
            aS0 = fS[(rg * 2 + 0) * 64 + lane];
            aS1 = fS[(rg * 2 + 1) * 64 + lane];
            aD  = fDA[rg * 64 + lane];
            rg_cur = rg;
        }
        bh8 bS0 = fS[(cg * 2 + 0) * 64 + lane];
        bh8 bS1 = fS[(cg * 2 + 1) * 64 + lane];
        bh8 bD  = fDB[cg * 64 + lane];

        fx16 accS = {0.f};
        accS = __builtin_amdgcn_mfma_f32_32x32x16_bf16(aS0, bS0, accS, 0, 0, 0);
        accS = __builtin_amdgcn_mfma_f32_32x32x16_bf16(aS1, bS1, accS, 0, 0, 0);
        fx16 accD = {0.f};
        accD = __builtin_amdgcn_mfma_f32_32x32x16_bf16(aD, bD, accD, 0, 0, 0);

        if (rg == cg) {
#pragma unroll
            for (int r2 = 0; r2 < 16; ++r2) {
                bool c = accD[r2] > 4.0f;
                psD += c ? fmaxf(accS[r2], 0.f) : 0.f;
                cnD += c ? 1 : 0;
            }
        } else {
#pragma unroll
            for (int r2 = 0; r2 < 16; ++r2) {
                bool c = accD[r2] > 4.0f;
                psO += c ? fmaxf(accS[r2], 0.f) : 0.f;
                cnO += c ? 1 : 0;
            }
        }
    }

    // fold x2 off-diagonal weight once, then reduce
    float ps = psD + 2.0f * psO;
    int   cn = cnD + 2 * cnO;
#pragma unroll
    for (int off = 32; off > 0; off >>= 1) {
        ps += __shfl_down(ps, off);
        cn += __shfl_down(cn, off);
    }
    __shared__ float sps[4];
    __shared__ int   scs[4];
    int wid = tid >> 6;
    if (lane == 0) { sps[wid] = ps; scs[wid] = cn; }
    __syncthreads();
    if (tid == 0) {
        psums[blockIdx.x] = sps[0] + sps[1] + sps[2] + sps[3];
        pcnts[blockIdx.x] = scs[0] + scs[1] + scs[2] + scs[3];
    }
}

__global__ void __launch_bounds__(256) fcl_final(const float* __restrict__ psums,
                                                 const int* __restrict__ pcnts,
                                                 float* __restrict__ out, int nb) {
    float s = 0.f;
    int c = 0;
    for (int k = threadIdx.x; k < nb; k += 256) { s += psums[k]; c += pcnts[k]; }
#pragma unroll
    for (int off = 32; off > 0; off >>= 1) {
        s += __shfl_down(s, off);
        c += __shfl_down(c, off);
    }
    __shared__ float sps[4];
    __shared__ int   scs[4];
    int wid = threadIdx.x >> 6, lane = threadIdx.x & 63;
    if (lane == 0) { sps[wid] = s; scs[wid] = c; }
    __syncthreads();
    if (threadIdx.x == 0) {
        float ts = sps[0] + sps[1] + sps[2] + sps[3];
        int   tc = scs[0] + scs[1] + scs[2] + scs[3];
        out[0] = (tc > 0) ? ts / (float)tc : 1.0f;
    }
}

extern "C" void kernel_launch(void* const* d_in, const int* in_sizes, int n_in,
                              void* d_out, int out_size, void* d_ws, size_t ws_size,
                              hipStream_t stream) {
    const float* pc     = (const float*)d_in[0];  // [N,3]
    const float* logits = (const float*)d_in[1];  // [N,20]
    float* out = (float*)d_out;

    const int N = in_sizes[0] / 3;                // 8192
    const int NG = N / 32;                        // 256 groups
    const int T = NG * (NG + 1) / 2;              // 32896 upper-tri tiles

    short* fragS  = (short*)d_ws;                 // 262144 shorts (512 KB)
    short* fragDA = fragS + 262144;               // 131072 shorts (256 KB)
    short* fragDB = fragDA + 131072;              // 131072 shorts (256 KB)
    float* psums  = (float*)(fragDB + 131072);
    const int nwaves  = (T + 7) / 8;              // 4112
    const int nblocks = (nwaves + 3) / 4;         // 1028
    int*   pcnts  = (int*)(psums + nblocks);

    fcl_prep<<<(N + 255) / 256, 256, 0, stream>>>(pc, logits, fragS, fragDA, fragDB, N);
    fcl_pairs<<<nblocks, 256, 0, stream>>>(fragS, fragDA, fragDB, psums, pcnts, NG, T);
    fcl_final<<<1, 256, 0, stream>>>(psums, pcnts, out, nblocks);
}

// Round 12
// 25.744 us; speedup vs baseline: 2.2141x; 1.0023x over previous
//
#include <hip/hip_runtime.h>

// ForegroundConsistencyLoss — N=8192, C=20.
// loss = mean over pairs {both fg, d2>4} of relu(cos_sim(logits_i, logits_j)).
//
// v5: row-chunked triangle enumeration. Each wave = 8 consecutive tiles in
// ONE row (A loaded once; B loads contiguous, batched, fully unrolled; diag
// check is compile-time k==0 && wave-uniform). v4 post-mortem: per-tile
// while/branches serialized loads against epilogue -> 19 us; this removes
// every per-tile scalar op.
//
// MFMA: sim = LN·LN^T (K=20 pad 32, bf16); d2 via augmented operands
// A'=[-2x,-2y,-2z,sq',1], B'=[x,y,z,1,sq'], sq' = fg ? |p|^2 : -1e30.
// Fragment convention + triangle weighting verified (absmax 0.0, r8/r9/r11).
// Reduction: per-block partials, zero contended atomics (v3 lesson).

#define C_CLS 20

typedef __attribute__((ext_vector_type(8)))  short bh8;    // 8 bf16 (4 VGPRs)
typedef __attribute__((ext_vector_type(16))) float fx16;   // 16 f32 acc
typedef __attribute__((ext_vector_type(4)))  float f4;

static __device__ __forceinline__ short f2bf(float x) {
    unsigned u = __float_as_uint(x);
    unsigned r = (u + 0x7fffu + ((u >> 16) & 1u)) >> 16;
    return (short)r;
}

// f(M) = sum_{m=1..M} ceil(m/8) = 4t(t+1) + s(t+1), t=M>>3, s=M&7
static __device__ __forceinline__ int fsum8(int M) {
    int t = M >> 3, s = M & 7;
    return 4 * t * (t + 1) + s * (t + 1);
}

__global__ void __launch_bounds__(256) fcl_prep(const float* __restrict__ pc,
                                                const float* __restrict__ logits,
                                                short* __restrict__ fragS,
                                                short* __restrict__ fragDA,
                                                short* __restrict__ fragDB, int n) {
    int i = blockIdx.x * blockDim.x + threadIdx.x;
    if (i >= n) return;
    const f4* lg4 = (const f4*)(logits + (size_t)i * C_CLS);  // 80B stride, 16B aligned
    float l[C_CLS];
#pragma unroll
    for (int q = 0; q < 5; ++q) {
        f4 v = lg4[q];
        l[q * 4 + 0] = v.x; l[q * 4 + 1] = v.y; l[q * 4 + 2] = v.z; l[q * 4 + 3] = v.w;
    }
    float m = l[1];
#pragma unroll
    for (int k = 2; k < C_CLS; ++k) m = fmaxf(m, l[k]);
    bool fg = m > l[0];                 // argmax != 0 (ties -> index 0 -> bg)
    float ss = 0.f;
#pragma unroll
    for (int k = 0; k < C_CLS; ++k) ss = fmaf(l[k], l[k], ss);
    float inv = 1.0f / fmaxf(sqrtf(ss), 1e-8f);
    float px = pc[i * 3 + 0], py = pc[i * 3 + 1], pz = pc[i * 3 + 2];
    float sq = px * px + py * py + pz * pz;
    float sqp = fg ? sq : -1.0e30f;

    int g = i >> 5, r = i & 31;
    bh8* fS8  = (bh8*)fragS;
    bh8* fDA8 = (bh8*)fragDA;
    bh8* fDB8 = (bh8*)fragDB;

    bh8 v0, v1, v2, vz = {0,0,0,0,0,0,0,0};
#pragma unroll
    for (int e = 0; e < 8; ++e) v0[e] = f2bf(l[e] * inv);
#pragma unroll
    for (int e = 0; e < 8; ++e) v1[e] = f2bf(l[8 + e] * inv);
#pragma unroll
    for (int e = 0; e < 8; ++e) v2[e] = (e < 4) ? f2bf(l[16 + e] * inv) : (short)0;
    fS8[(g * 2 + 0) * 64 + r]      = v0;   // k 0..7
    fS8[(g * 2 + 0) * 64 + r + 32] = v1;   // k 8..15
    fS8[(g * 2 + 1) * 64 + r]      = v2;   // k 16..23 (pad)
    fS8[(g * 2 + 1) * 64 + r + 32] = vz;   // k 24..31 (pad)

    bh8 da = vz, db = vz;
    da[0] = f2bf(-2.0f * px); da[1] = f2bf(-2.0f * py); da[2] = f2bf(-2.0f * pz);
    da[3] = f2bf(sqp);        da[4] = f2bf(1.0f);
    db[0] = f2bf(px); db[1] = f2bf(py); db[2] = f2bf(pz);
    db[3] = f2bf(1.0f); db[4] = f2bf(sqp);
    fDA8[g * 64 + r]      = da;
    fDA8[g * 64 + r + 32] = vz;
    fDB8[g * 64 + r]      = db;
    fDB8[g * 64 + r + 32] = vz;
}

// chunk c -> (rg, cg0): rows chunked independently, 8 tiles per chunk.
// Cpre(rg) = f(NG) - f(NG-rg) chunks precede row rg.
__global__ void __launch_bounds__(256) fcl_pairs(const short* __restrict__ fragS,
                                                 const short* __restrict__ fragDA,
                                                 const short* __restrict__ fragDB,
                                                 float* __restrict__ psums,
                                                 int* __restrict__ pcnts,
                                                 int NG, int Tc) {
    const int tid = threadIdx.x;
    const int lane = tid & 63;
    const int c = blockIdx.x * 4 + (tid >> 6);

    float psD = 0.f, psO = 0.f;
    int   cnD = 0,   cnO = 0;

    if (c < Tc) {
        const int fNG = fsum8(NG);
        int lo = 0, hi = NG - 1;
#pragma unroll 8
        while (lo < hi) {                       // find max rg with Cpre(rg) <= c
            int mid = (lo + hi + 1) >> 1;
            int cp = fNG - fsum8(NG - mid);
            if (cp <= c) lo = mid; else hi = mid - 1;
        }
        const int rg  = lo;
        const int cg0 = rg + ((c - (fNG - fsum8(NG - rg))) << 3);
        const bool hasDiag = (cg0 == rg);

        const bh8* fS  = (const bh8*)fragS;
        const bh8* fDA = (const bh8*)fragDA;
        const bh8* fDB = (const bh8*)fragDB;

        const bh8 aS0 = fS[(rg * 2 + 0) * 64 + lane];
        const bh8 aS1 = fS[(rg * 2 + 1) * 64 + lane];
        const bh8 aD  = fDA[rg * 64 + lane];

#pragma unroll
        for (int h = 0; h < 2; ++h) {
            bh8 b0[4], b1[4], bd[4];
#pragma unroll
            for (int k = 0; k < 4; ++k) {
                int cg = cg0 + h * 4 + k;
                int cgc = (cg < NG) ? cg : (NG - 1);   // clamped load, masked epilogue
                b0[k] = fS[(cgc * 2 + 0) * 64 + lane];
                b1[k] = fS[(cgc * 2 + 1) * 64 + lane];
                bd[k] = fDB[cgc * 64 + lane];
            }
#pragma unroll
            for (int k = 0; k < 4; ++k) {
                int cg = cg0 + h * 4 + k;
                if (cg < NG) {                          // wave-uniform
                    fx16 accS = {0.f};
                    accS = __builtin_amdgcn_mfma_f32_32x32x16_bf16(aS0, b0[k], accS, 0, 0, 0);
                    accS = __builtin_amdgcn_mfma_f32_32x32x16_bf16(aS1, b1[k], accS, 0, 0, 0);
                    fx16 accD = {0.f};
                    accD = __builtin_amdgcn_mfma_f32_32x32x16_bf16(aD, bd[k], accD, 0, 0, 0);
                    if (h == 0 && k == 0 && hasDiag) {  // compile-time x uniform
#pragma unroll
                        for (int r2 = 0; r2 < 16; ++r2) {
                            bool cc = accD[r2] > 4.0f;
                            psD += cc ? fmaxf(accS[r2], 0.f) : 0.f;
                            cnD += cc ? 1 : 0;
                        }
                    } else {
#pragma unroll
                        for (int r2 = 0; r2 < 16; ++r2) {
                            bool cc = accD[r2] > 4.0f;
                            psO += cc ? fmaxf(accS[r2], 0.f) : 0.f;
                            cnO += cc ? 1 : 0;
                        }
                    }
                }
            }
        }
    }

    // fold x2 off-diagonal weight, then wave + block reduce
    float ps = psD + 2.0f * psO;
    int   cn = cnD + 2 * cnO;
#pragma unroll
    for (int off = 32; off > 0; off >>= 1) {
        ps += __shfl_down(ps, off);
        cn += __shfl_down(cn, off);
    }
    __shared__ float sps[4];
    __shared__ int   scs[4];
    int wid = tid >> 6;
    if (lane == 0) { sps[wid] = ps; scs[wid] = cn; }
    __syncthreads();
    if (tid == 0) {
        psums[blockIdx.x] = sps[0] + sps[1] + sps[2] + sps[3];
        pcnts[blockIdx.x] = scs[0] + scs[1] + scs[2] + scs[3];
    }
}

__global__ void __launch_bounds__(256) fcl_final(const float* __restrict__ psums,
                                                 const int* __restrict__ pcnts,
                                                 float* __restrict__ out, int nb) {
    float s = 0.f;
    int c = 0;
    for (int k = threadIdx.x; k < nb; k += 256) { s += psums[k]; c += pcnts[k]; }
#pragma unroll
    for (int off = 32; off > 0; off >>= 1) {
        s += __shfl_down(s, off);
        c += __shfl_down(c, off);
    }
    __shared__ float sps[4];
    __shared__ int   scs[4];
    int wid = threadIdx.x >> 6, lane = threadIdx.x & 63;
    if (lane == 0) { sps[wid] = s; scs[wid] = c; }
    __syncthreads();
    if (threadIdx.x == 0) {
        float ts = sps[0] + sps[1] + sps[2] + sps[3];
        int   tc = scs[0] + scs[1] + scs[2] + scs[3];
        out[0] = (tc > 0) ? ts / (float)tc : 1.0f;
    }
}

extern "C" void kernel_launch(void* const* d_in, const int* in_sizes, int n_in,
                              void* d_out, int out_size, void* d_ws, size_t ws_size,
                              hipStream_t stream) {
    const float* pc     = (const float*)d_in[0];  // [N,3]
    const float* logits = (const float*)d_in[1];  // [N,20]
    float* out = (float*)d_out;

    const int N = in_sizes[0] / 3;                // 8192
    const int NG = N / 32;                        // 256 groups
    // total row-chunks: f(NG) with f(M)=sum ceil(m/8)
    int tt = NG >> 3, st = NG & 7;
    const int Tc = 4 * tt * (tt + 1) + st * (tt + 1);   // 4224 for NG=256

    short* fragS  = (short*)d_ws;                 // 262144 shorts (512 KB)
    short* fragDA = fragS + 262144;               // 131072 shorts (256 KB)
    short* fragDB = fragDA + 131072;              // 131072 shorts (256 KB)
    float* psums  = (float*)(fragDB + 131072);
    const int nblocks = (Tc + 3) / 4;             // 1056
    int*   pcnts  = (int*)(psums + nblocks);

    fcl_prep<<<(N + 255) / 256, 256, 0, stream>>>(pc, logits, fragS, fragDA, fragDB, N);
    fcl_pairs<<<nblocks, 256, 0, stream>>>(fragS, fragDA, fragDB, psums, pcnts, NG, Tc);
    fcl_final<<<1, 256, 0, stream>>>(psums, pcnts, out, nblocks);
}